// Round 8
// baseline (1496.037 us; speedup 1.0000x reference)
//
#include <hip/hip_runtime.h>
#include <stdint.h>

#define H 512
#define B_SZ 1024
#define T_WARM 256
#define NSTEPS 64
#define TLOOP (T_WARM + NSTEPS - 1)   // 319 steps; epilogue of t makes h(t+1), y(t+1)

#define RPB 16          // rows per team
#define NTEAM 64        // B_SZ / RPB
#define NCG 4           // col groups (blocks per team)
#define NBLK 256        // NTEAM * NCG == CU count, 1 block/CU
#define NTHR 512        // 8 waves = 4 col-groups (g) x 2 K-halves (kh)
#define ROWB 1024       // LDS h row stride bytes; swizzle byte ^= (row&7)<<4 both sides
#define HC 128          // tr scratch cols (u32 packed)
#define REDS 20         // partial-exchange row stride (words)

typedef __attribute__((ext_vector_type(8))) short bf16x8;
typedef __attribute__((ext_vector_type(4))) float f32x4;

static __device__ __forceinline__ ushort f2bf(float f) {
    uint32_t u = __builtin_bit_cast(uint32_t, f);
    u += 0x7FFFu + ((u >> 16) & 1u);
    return (ushort)(u >> 16);
}
static __device__ __forceinline__ float bf2f(ushort h) {
    uint32_t u = ((uint32_t)h) << 16;
    return __builtin_bit_cast(float, u);
}

__global__ void prep_kernel(const float* __restrict__ x,
                            const float* __restrict__ W_hh,
                            const float* __restrict__ b_ih,
                            const float* __restrict__ b_hh,
                            ushort* __restrict__ Wh, ushort* __restrict__ Wl,
                            float* __restrict__ bias, float* __restrict__ xT,
                            uint32_t* __restrict__ Hb0, float* __restrict__ Yacc,
                            uint32_t* __restrict__ flags) {
    int i = blockIdx.x * NTHR + threadIdx.x;     // [0, 524288)
    Hb0[i] = 0u;                                  // h(0) = 0 (packed hi|lo)
    if (i < 4096) flags[i] = 0u;
    if (i < B_SZ * NSTEPS) Yacc[i] = 0.f;
    if (i < H * H) {
        float w = W_hh[i];
        ushort hi = f2bf(w);
        Wh[i] = hi;
        Wl[i] = f2bf(w - bf2f(hi));
    }
    if (i < B_SZ * T_WARM) {
        int b = i & (B_SZ - 1), t = i >> 10;
        xT[t * B_SZ + b] = x[b * T_WARM + t];
    }
    if (i < H) bias[i] = b_ih[i] + b_hh[i];
}

__global__ void fix_kernel(const float* __restrict__ Yacc,
                           const float* __restrict__ b_fc_p,
                           float* __restrict__ out) {
    int i = blockIdx.x * 256 + threadIdx.x;      // 65536 = B_SZ*NSTEPS
    out[i] = Yacc[i] + b_fc_p[0];
}

// R0 skeleton (packed-u32 comm, tr self scratch, barrier-I drain, 1 flag/block)
// + K-split waves (32 cols x K=256 -> half the LDS A-reads, sym. partial
// exchange) + rank-1 y-fold (rollout == warm; y via LDS accum + end atomics).
__global__ __launch_bounds__(NTHR, 1)
void rnn_kernel(const float* __restrict__ xT,
                const float* __restrict__ W_ih,
                const float* __restrict__ b_fc_p,
                const float* __restrict__ W_fc,
                const ushort* __restrict__ Wh_g,
                const ushort* __restrict__ Wl_g,
                const float* __restrict__ bias_g,
                uint32_t* __restrict__ Hb0, uint32_t* __restrict__ Hb1,
                uint32_t* __restrict__ flags,
                float* __restrict__ Yacc) {
    __shared__ __align__(16) ushort h_hi[2][RPB * 512];   // ping-pong hi, 16 KB each
    __shared__ __align__(16) ushort h_lo[2][RPB * 512];   // ping-pong lo
    __shared__ uint32_t tr[RPB * HC];                     // self-slice scratch, 8 KB
    __shared__ __align__(16) float red_s[8 * RPB * REDS]; // K-half partials, 10 KB
    __shared__ __align__(16) float w_fc_s[H];
    __shared__ float yacc_s[NSTEPS * RPB];                // y accum [step][row], 4 KB

    const int tid  = threadIdx.x;
    const int bid  = blockIdx.x;
    const int team = bid & (NTEAM - 1);   // blocks {team,+64,+128,+192}: same XCD
    const int cg   = bid >> 6;            // 0..3
    const int row0 = team * RPB;
    const int col0 = cg * 128;

    const int lane = tid & 63;
    const int wv   = tid >> 6;            // 0..7; also staged 64-col slice id
    const int g    = wv & 3;              // col-group: cols [col0+32g, +32)
    const int kh   = wv >> 2;             // K-half: k in [256kh, +256)
    const int n    = lane & 15, q = lane >> 4;
    const bool selfw = ((wv >> 1) == cg); // staged slice produced by own block

    w_fc_s[tid] = W_fc[tid];
    for (int i = tid; i < RPB * 512; i += NTHR) { h_hi[0][i] = 0; h_lo[0][i] = 0; }
    for (int i = tid; i < NSTEPS * RPB; i += NTHR) yacc_s[i] = 0.f;

    // ---- weights register-resident: 2 col-tiles x 8 kt (K=256), hi+lo = 128 regs ----
    bf16x8 Bh0[8], Bl0[8], Bh1[8], Bl1[8];
    const int j0 = col0 + g * 32 + n;     // tile0 col
    const int j1 = j0 + 16;               // tile1 col
    {
        const ushort* p0h = Wh_g + j0 * H + kh * 256 + q * 8;
        const ushort* p0l = Wl_g + j0 * H + kh * 256 + q * 8;
        const ushort* p1h = Wh_g + j1 * H + kh * 256 + q * 8;
        const ushort* p1l = Wl_g + j1 * H + kh * 256 + q * 8;
        #pragma unroll
        for (int kt = 0; kt < 8; ++kt) {
            Bh0[kt] = *(const bf16x8*)(p0h + kt * 32);
            Bl0[kt] = *(const bf16x8*)(p0l + kt * 32);
            Bh1[kt] = *(const bf16x8*)(p1h + kt * 32);
            Bl1[kt] = *(const bf16x8*)(p1l + kt * 32);
        }
    }
    const int jf = col0 + g * 32 + kh * 16 + n;   // this lane's FINALIZED col
    const float wi0 = W_ih[j0], wi1 = W_ih[j1];
    const float wif = kh ? wi1 : wi0;
    const float wfcj = W_fc[jf];
    float bj = bias_g[jf];
    const float bfc = b_fc_p[0];

    uint32_t* const myflag = flags + (team * NCG + cg) * 16;
    const uint32_t* const pollflag = flags + (team * NCG + (wv >> 1)) * 16;

    char* const hb0c = (char*)&h_hi[0][0];
    char* const hb1c = (char*)&h_hi[1][0];
    char* const lb0c = (char*)&h_lo[0][0];
    char* const lb1c = (char*)&h_lo[1][0];

    __syncthreads();

    for (int t = 0; t < TLOOP; ++t) {
        const int pp = t & 1;
        const bool roll = (t >= T_WARM);

        // ---- one-time rank-1 fold: W' = W + w_in (x) wfc, bias' = bias + bfc*w_in ----
        if (t == T_WARM) {
            #pragma unroll
            for (int kt = 0; kt < 8; ++kt) {
                const float* wf = &w_fc_s[kh * 256 + kt * 32 + q * 8];
                f32x4 w0v = *(const f32x4*)wf;
                f32x4 w1v = *(const f32x4*)(wf + 4);
                #pragma unroll
                for (int j = 0; j < 8; ++j) {
                    const float wk = (j < 4) ? w0v[j] : w1v[j - 4];
                    {
                        float v = bf2f((ushort)Bh0[kt][j]) + bf2f((ushort)Bl0[kt][j]) + wi0 * wk;
                        const ushort hb = f2bf(v);
                        Bh0[kt][j] = (short)hb;
                        Bl0[kt][j] = (short)f2bf(v - bf2f(hb));
                    }
                    {
                        float v = bf2f((ushort)Bh1[kt][j]) + bf2f((ushort)Bl1[kt][j]) + wi1 * wk;
                        const ushort hb = f2bf(v);
                        Bh1[kt][j] = (short)hb;
                        Bl1[kt][j] = (short)f2bf(v - bf2f(hb));
                    }
                }
            }
            bj += bfc * wif;
        }

        f32x4 xq = {0.f, 0.f, 0.f, 0.f};
        if (!roll) xq = *(const f32x4*)(xT + t * B_SZ + row0 + q * 4);

        // ---- acquire slice s=wv: self -> tr scratch, remote -> poll + L2 ----
        uint64_t tmp[8];
        if (t > 0 && selfw) {
            #pragma unroll
            for (int it = 0; it < 8; ++it) {
                int idx = it * 64 + lane;
                int r = idx >> 5, c = idx & 31;
                int kloc = (wv & 1) * 64 + c * 2;
                const uint32_t* p = &tr[r * HC + kloc];
                tmp[it] = (uint64_t)p[0] | ((uint64_t)p[1] << 32);
            }
        } else {
            if (t > 0) {
                while (__hip_atomic_load(pollflag, __ATOMIC_RELAXED, __HIP_MEMORY_SCOPE_AGENT)
                       < (uint32_t)t)
                    __builtin_amdgcn_s_sleep(1);
            }
            const uint64_t* src = (const uint64_t*)((t & 1) ? Hb1 : Hb0);
            #pragma unroll
            for (int it = 0; it < 8; ++it) {
                int idx = it * 64 + lane;
                int r = idx >> 5, c = idx & 31;
                tmp[it] = __hip_atomic_load(src + ((row0 + r) * 256 + wv * 32 + c),
                                            __ATOMIC_RELAXED, __HIP_MEMORY_SCOPE_AGENT);
            }
        }
        // ---- unpack into LDS buf pp (swizzled) ----
        {
            char* hb = pp ? hb1c : hb0c;
            char* lb = pp ? lb1c : lb0c;
            #pragma unroll
            for (int it = 0; it < 8; ++it) {
                int idx = it * 64 + lane;
                int r = idx >> 5, c = idx & 31;
                int byte = (r * ROWB + wv * 128 + c * 4) ^ ((r & 7) << 4);
                uint64_t u = tmp[it];
                uint32_t w0 = (uint32_t)u, w1 = (uint32_t)(u >> 32);
                *(uint32_t*)(hb + byte) = (w0 >> 16) | (w1 & 0xFFFF0000u);
                *(uint32_t*)(lb + byte) = (w0 & 0xFFFFu) | (w1 << 16);
            }
        }
        __syncthreads();   // E: all slices staged

        // ---- MFMA: 2 col-tiles x 8 kt x 3 terms; 2 b128 reads feed 6 MFMAs ----
        const char* ha = pp ? hb1c : hb0c;
        const char* la = pp ? lb1c : lb0c;
        const int aoffs = n * ROWB + q * 16 + kh * 512;   // kh*256 cols * 2B
        const int aswz  = (n & 7) << 4;
        f32x4 a0 = {0.f, 0.f, 0.f, 0.f}, a1 = {0.f, 0.f, 0.f, 0.f};
        #pragma unroll
        for (int kt = 0; kt < 8; ++kt) {
            const int b0 = (aoffs + kt * 64) ^ aswz;
            bf16x8 ah = *(const bf16x8*)(ha + b0);
            bf16x8 al = *(const bf16x8*)(la + b0);
            a0 = __builtin_amdgcn_mfma_f32_16x16x32_bf16(ah, Bh0[kt], a0, 0, 0, 0);
            a1 = __builtin_amdgcn_mfma_f32_16x16x32_bf16(ah, Bh1[kt], a1, 0, 0, 0);
            a0 = __builtin_amdgcn_mfma_f32_16x16x32_bf16(al, Bh0[kt], a0, 0, 0, 0);
            a1 = __builtin_amdgcn_mfma_f32_16x16x32_bf16(al, Bh1[kt], a1, 0, 0, 0);
            a0 = __builtin_amdgcn_mfma_f32_16x16x32_bf16(ah, Bl0[kt], a0, 0, 0, 0);
            a1 = __builtin_amdgcn_mfma_f32_16x16x32_bf16(ah, Bl1[kt], a1, 0, 0, 0);
        }

        // ---- K-half partial exchange: deposit non-finalized tile ----
        {
            const f32x4 adep = kh ? a0 : a1;
            float* dep = &red_s[(g * 2 + (kh ^ 1)) * RPB * REDS];
            #pragma unroll
            for (int i = 0; i < 4; ++i) dep[(q * 4 + i) * REDS + n] = adep[i];
        }
        __syncthreads();   // R: partials visible
        const f32x4 aown = kh ? a1 : a0;
        const float* par = &red_s[(g * 2 + kh) * RPB * REDS];

        // ---- epilogue: v = own + partner + (x*w_in) + bias', relu, publish ----
        const bool capy = (t >= T_WARM - 1);
        uint32_t* hbn = (t & 1) ? Hb0 : Hb1;
        const int jl = g * 32 + kh * 16 + n;          // local col of finalized lane
        float sarr[4];
        #pragma unroll
        for (int i = 0; i < 4; ++i) {
            const int m = q * 4 + i;                  // C/D: row = quad*4+reg, col = n
            float v = aown[i] + par[m * REDS + n] + bj;
            if (!roll) v += xq[i] * wif;
            v = fmaxf(v, 0.f);
            sarr[i] = v * wfcj;
            const ushort hb16 = f2bf(v);
            const ushort lb16 = f2bf(v - bf2f(hb16));
            const uint32_t pk = ((uint32_t)hb16 << 16) | lb16;
            tr[m * HC + jl] = pk;                     // self scratch for next step
            __hip_atomic_store(hbn + (row0 + m) * H + col0 + jl, pk,
                               __ATOMIC_RELAXED, __HIP_MEMORY_SCOPE_AGENT);
        }
        if (capy) {
            #pragma unroll
            for (int i = 0; i < 4; ++i) {
                float s = sarr[i];
                s += __shfl_xor(s, 1); s += __shfl_xor(s, 2);
                s += __shfl_xor(s, 4); s += __shfl_xor(s, 8);
                if (n == 0)
                    atomicAdd(&yacc_s[(t + 1 - T_WARM) * RPB + q * 4 + i], s);
            }
        }
        __syncthreads();   // I: drains global stores (vmcnt0) + orders tr
        if (tid == 0)
            __hip_atomic_store(myflag, (uint32_t)(t + 1),
                               __ATOMIC_RELAXED, __HIP_MEMORY_SCOPE_AGENT);
    }

    // ---- one-time y sweep: block's 128-col partials -> global accum ----
    __syncthreads();
    for (int i = tid; i < NSTEPS * RPB; i += NTHR) {
        const int s = i >> 4, r = i & 15;
        atomicAdd(&Yacc[(size_t)(row0 + r) * NSTEPS + s], yacc_s[i]);
    }
}

extern "C" void kernel_launch(void* const* d_in, const int* in_sizes, int n_in,
                              void* d_out, int out_size, void* d_ws, size_t ws_size,
                              hipStream_t stream) {
    const float* x    = (const float*)d_in[0];
    const float* W_ih = (const float*)d_in[1];
    const float* W_hh = (const float*)d_in[2];
    const float* b_ih = (const float*)d_in[3];
    const float* b_hh = (const float*)d_in[4];
    const float* W_fc = (const float*)d_in[5];
    const float* b_fc = (const float*)d_in[6];
    float* out = (float*)d_out;

    // ws carve (bytes): Wh 512K | Wl 512K | bias 4K | xT 1M | Hb0 2M | Hb1 2M |
    //                   flags 16K | Yacc 256K   (~6.5 MB)
    uint8_t* w = (uint8_t*)d_ws;
    ushort*   Wh    = (ushort*)(w);
    ushort*   Wl    = (ushort*)(w + 524288);
    float*    bias  = (float*)(w + 1048576);
    float*    xT    = (float*)(w + 1052672);
    uint32_t* Hb0   = (uint32_t*)(w + 2101248);
    uint32_t* Hb1   = (uint32_t*)(w + 4198400);
    uint32_t* flags = (uint32_t*)(w + 6295552);
    float*    Yacc  = (float*)(w + 6311936);

    prep_kernel<<<1024, NTHR, 0, stream>>>(x, W_hh, b_ih, b_hh, Wh, Wl, bias, xT,
                                           Hb0, Yacc, flags);
    rnn_kernel<<<NBLK, NTHR, 0, stream>>>(xT, W_ih, b_fc, W_fc, Wh, Wl, bias,
                                          Hb0, Hb1, flags, Yacc);
    fix_kernel<<<256, 256, 0, stream>>>(Yacc, b_fc, out);
}